// Round 2
// baseline (645.587 us; speedup 1.0000x reference)
//
#include <hip/hip_runtime.h>
#include <math.h>

#define BATCH  64
#define SEQ    8192
#define DIM    128
#define SPLITS 32
#define CHUNK  (SEQ / SPLITS)   // 256 positions per block
#define WPOS   (CHUNK / 4)      // 64 positions per wave
#define ITERS  (WPOS / 2)       // 32 iterations x 2 positions
#define SCALE  0.08838834764831845f  // 1/sqrt(128)
#define PSTRIDE 132             // per-partial floats: l, o[128], pad

// R4 theory: R1 counters showed latency-bound streaming (hbm 21% peak,
// VALUBusy 4%, Occupancy 21%, VGPR 92 -> 5 waves/SIMD ceiling, ~7 resident
// waves/CU). Too few in-flight bytes to cover ~1500cy loaded HBM latency.
// Fix: lean mapping (2 positions/iter, lane owns 4 dims) cuts register
// state ~in half; __launch_bounds__(256,8) pins VGPR<=64 -> 8 waves/SIMD
// = 32 waves/CU = exactly one full-residency round for the 8192-wave grid.
// Each global_load_dwordx4 covers 1KB fully contiguous (2 rows x 512B).
__global__ __launch_bounds__(256, 8) void attn_partial_kernel(
    const float* __restrict__ q, const float* __restrict__ k,
    const float* __restrict__ v, float* __restrict__ scores_out,
    float* __restrict__ partials)
{
    const int b     = blockIdx.y;
    const int split = blockIdx.x;
    const int tid   = threadIdx.x;
    const int wave  = tid >> 6;
    const int lane  = tid & 63;
    const int g     = lane >> 5;   // position within pair (0..1)
    const int t     = lane & 31;   // dim quad: dims [4t, 4t+4)

    __shared__ float ssc[CHUNK];      // unnormalized exp-scores
    __shared__ float so[4][DIM];
    __shared__ float sl[4];

    const float4 qa = *(const float4*)(q + (size_t)b * DIM + 4 * t);

    const int s_wbase = split * CHUNK + wave * WPOS;
    const float* kp = k + ((size_t)b * SEQ + s_wbase + g) * DIM + 4 * t;
    const float* vp = v + ((size_t)b * SEQ + s_wbase + g) * DIM + 4 * t;

    float  l = 0.f;
    float4 o = make_float4(0.f, 0.f, 0.f, 0.f);

    // 2-deep register prefetch (iters 0 and 1)
    float4 k0 = *(const float4*)(kp);
    float4 v0 = *(const float4*)(vp);
    float4 k1 = *(const float4*)(kp + 2 * DIM);
    float4 v1 = *(const float4*)(vp + 2 * DIM);
    kp += 4 * DIM;   // -> iter 2
    vp += 4 * DIM;

    #pragma unroll
    for (int i = 0; i < ITERS; ++i) {
        float4 kn, vn;
        if (i + 2 < ITERS) {          // static after full unroll
            kn = *(const float4*)(kp);
            vn = *(const float4*)(vp);
            kp += 2 * DIM;
            vp += 2 * DIM;
        }

        // partial dot over this lane's 4 dims
        float p = fmaf(qa.x, k0.x, qa.y * k0.y);
        p = fmaf(qa.z, k0.z, p);
        p = fmaf(qa.w, k0.w, p);
        // butterfly reduce across the 32 lanes of this half (all 128 dims)
        p += __shfl_xor(p, 1, 64);
        p += __shfl_xor(p, 2, 64);
        p += __shfl_xor(p, 4, 64);
        p += __shfl_xor(p, 8, 64);
        p += __shfl_xor(p, 16, 64);

        const float e = __expf(p * SCALE);
        if (t == 0) ssc[wave * WPOS + 2 * i + g] = e;

        l += e;
        o.x = fmaf(e, v0.x, o.x);
        o.y = fmaf(e, v0.y, o.y);
        o.z = fmaf(e, v0.z, o.z);
        o.w = fmaf(e, v0.w, o.w);

        k0 = k1; v0 = v1; k1 = kn; v1 = vn;
    }

    // combine the two position-halves (same dims in lanes t and t+32)
    l   += __shfl_xor(l,   32, 64);
    o.x += __shfl_xor(o.x, 32, 64);
    o.y += __shfl_xor(o.y, 32, 64);
    o.z += __shfl_xor(o.z, 32, 64);
    o.w += __shfl_xor(o.w, 32, 64);

    if (g == 0) {
        *(float4*)&so[wave][4 * t] = o;
        if (t == 0) sl[wave] = l;
    }
    __syncthreads();

    // coalesced score dump: 256 threads x 4 B = 1 KB
    scores_out[(size_t)b * SEQ + split * CHUNK + tid] = ssc[tid];

    float* part = partials + ((size_t)b * SPLITS + split) * PSTRIDE;
    if (tid < DIM) {
        part[1 + tid] = so[0][tid] + so[1][tid] + so[2][tid] + so[3][tid];
        if (tid == 0) part[0] = sl[0] + sl[1] + sl[2] + sl[3];
    }
}

// Kernel 2: per batch, sum the 32 split partials -> l, write attn_vec,
// normalize the unnormalized exp-scores into softmax weights. grid (4, BATCH).
__global__ __launch_bounds__(256) void attn_finalize_kernel(
    const float* __restrict__ partials, float* __restrict__ out_vec,
    float* __restrict__ weights /* exp-scores in, weights out */)
{
    const int b   = blockIdx.y;
    const int qx  = blockIdx.x;   // 0..3
    const int tid = threadIdx.x;

    const float* part = partials + (size_t)b * SPLITS * PSTRIDE;

    float l_g = 0.f;
    #pragma unroll
    for (int c = 0; c < SPLITS; ++c)
        l_g += part[c * PSTRIDE];
    const float inv_l = 1.f / l_g;

    if (qx == 0 && tid < DIM) {
        float acc = 0.f;
        #pragma unroll
        for (int c = 0; c < SPLITS; ++c)
            acc += part[c * PSTRIDE + 1 + tid];
        out_vec[(size_t)b * DIM + tid] = acc * inv_l;
    }

    const int per_block = SEQ / 4;   // 2048 floats = 512 float4
    float4* wrow = (float4*)(weights + (size_t)b * SEQ + (size_t)qx * per_block);
    for (int i = tid; i < per_block / 4; i += 256) {
        float4 w = wrow[i];
        w.x *= inv_l;
        w.y *= inv_l;
        w.z *= inv_l;
        w.w *= inv_l;
        wrow[i] = w;
    }
}

extern "C" void kernel_launch(void* const* d_in, const int* in_sizes, int n_in,
                              void* d_out, int out_size, void* d_ws, size_t ws_size,
                              hipStream_t stream) {
    const float* q = (const float*)d_in[0];   // [64, 1, 128]
    const float* k = (const float*)d_in[1];   // [64, 8192, 128]
    const float* v = (const float*)d_in[2];   // [64, 8192, 128]

    float* out      = (float*)d_out;
    float* out_vec  = out;                    // attn_vec: 64*128 floats
    float* out_w    = out + BATCH * DIM;      // attn_weight: 64*8192 floats
    float* partials = (float*)d_ws;           // 64*32*132 floats ≈ 1.08 MB

    attn_partial_kernel<<<dim3(SPLITS, BATCH), 256, 0, stream>>>(
        q, k, v, out_w, partials);
    attn_finalize_kernel<<<dim3(4, BATCH), 256, 0, stream>>>(
        partials, out_vec, out_w);
}